// Round 8
// baseline (3124.300 us; speedup 1.0000x reference)
//
#include <hip/hip_runtime.h>

#define N_NODES 50000
#define N_EDGES 1600000
#define NF 500
#define HID 64
#define NCLS 40
#define NT (N_NODES * HID)   // 3.2M
#define NBUCK 196            // ceil(N_NODES/256) destination buckets of 256 nodes
#define NFB 200              // fill blocks
#define EPB 8000             // edges per fill block (NFB*EPB == N_EDGES exact)
#define CNT_N (NBUCK * NFB)  // 39200
#define NSCB 154             // ceil(CNT_N/256)

typedef unsigned short ushort_t;
typedef unsigned int uint_t;
typedef __attribute__((ext_vector_type(8))) short short8;     // 8 bf16 (4 VGPRs)
typedef __attribute__((ext_vector_type(4))) float f32x4;      // MFMA acc

__device__ __forceinline__ float bf2f(ushort_t u) {
    union { uint_t i; float f; } v; v.i = ((uint_t)u) << 16; return v.f;
}
__device__ __forceinline__ ushort_t f2bf(float f) {
    union { float fl; uint_t i; } u; u.fl = f;
    uint_t lsb = (u.i >> 16) & 1u;
    return (ushort_t)((u.i + 0x7fffu + lsb) >> 16);   // RNE
}
__device__ __forceinline__ float2 bfpair2f2(uint_t u) {
    union { uint_t i; float f; } lo, hi;
    lo.i = (u & 0xffffu) << 16;
    hi.i = u & 0xffff0000u;
    float2 r; r.x = lo.f; r.y = hi.f; return r;
}

// scalar load/store for internal arrays: float (tier1) or bf16 (tier2)
template<typename T> __device__ __forceinline__ float ldv(const T* p);
template<> __device__ __forceinline__ float ldv<float>(const float* p) { return *p; }
template<> __device__ __forceinline__ float ldv<ushort_t>(const ushort_t* p) { return bf2f(*p); }
template<typename T> __device__ __forceinline__ void stv(T* p, float v);
template<> __device__ __forceinline__ void stv<float>(float* p, float v) { *p = v; }
template<> __device__ __forceinline__ void stv<ushort_t>(ushort_t* p, float v) { *p = f2bf(v); }

// dual-dtype input read (flag: 1 = f32, 0 = bf16)
__device__ __forceinline__ float ldin(const void* p, size_t idx, bool isf32) {
    return isf32 ? ((const float*)p)[idx] : bf2f(((const ushort_t*)p)[idx]);
}

// stage 16 input elements (global, dtype by flag) -> bf16 LDS
__device__ __forceinline__ void stage16_in(const void* src, size_t rowoff, int k0, int kmax,
                                           bool isf32, bool valid, ushort_t* dst) {
    if (valid && isf32 && (k0 + 16 <= kmax)) {
        const float4* p = (const float4*)((const float*)src + rowoff + k0);
        #pragma unroll
        for (int q = 0; q < 4; q++) {
            float4 v = p[q];
            dst[q * 4 + 0] = f2bf(v.x); dst[q * 4 + 1] = f2bf(v.y);
            dst[q * 4 + 2] = f2bf(v.z); dst[q * 4 + 3] = f2bf(v.w);
        }
    } else {
        #pragma unroll
        for (int i = 0; i < 16; i++) {
            int k = k0 + i;
            float v = (valid && k < kmax) ? ldin(src, rowoff + k, isf32) : 0.f;
            dst[i] = f2bf(v);
        }
    }
}

// ---------------- input dtype detector ----------------
__global__ void detect_k(const uint_t* __restrict__ xw, uint_t* __restrict__ flag) {
    __shared__ int cnt;
    if (threadIdx.x == 0) cnt = 0;
    __syncthreads();
    int odd = 0;
    for (int i = 0; i < 16; i++) {
        uint_t w = xw[threadIdx.x * 16 + i];
        uint_t e = (w >> 7) & 0xFFu;
        if (e > 170u || e < 84u) odd++;
    }
    atomicAdd(&cnt, odd);
    __syncthreads();
    if (threadIdx.x == 0) *flag = (cnt > 400) ? 1u : 0u;
}

// ---------------- W_eff build: 1 block x 64 ----------------
__global__ void build_W(const void* __restrict__ pw, const uint_t* __restrict__ flag,
                        float* __restrict__ W) {
    bool isf32 = (*flag != 0u);
    int i = threadIdx.x;
    float q = ldin(pw, i * 66 + 64, isf32);
    float r = ldin(pw, i * 66 + 65, isf32);
    float s = 0.f;
    for (int j = 0; j < 64; j++) {
        float v = 0.f;
        if (j > i)      v = ldin(pw, i * 66 + j, isf32);
        else if (j < i) v = ldin(pw, j * 66 + i, isf32);
        s += fabsf(v);
        W[i * 64 + j] = v;
    }
    W[i * 64 + i] = q * s + r;
}

// ---------------- bucketed edge build ----------------
// bcount: per-(fill-block, bucket) counts via LDS histogram
__global__ __launch_bounds__(256) void bcount(const int* __restrict__ col,
                                              int* __restrict__ cnt) {
    __shared__ int hist[NBUCK];
    int tid = threadIdx.x, blk = blockIdx.x;
    for (int i = tid; i < NBUCK; i += 256) hist[i] = 0;
    __syncthreads();
    int e0 = blk * EPB;
    for (int i = tid; i < EPB; i += 256)
        atomicAdd(&hist[col[e0 + i] >> 8], 1);
    __syncthreads();
    for (int i = tid; i < NBUCK; i += 256) cnt[i * NFB + blk] = hist[i];
}

// exclusive scan of cnt[CNT_N]: 3 kernels
__global__ __launch_bounds__(256) void scan_part2(const int* __restrict__ cnt,
                                                  int* __restrict__ part) {
    __shared__ int wsum[4];
    int i = blockIdx.x * 256 + threadIdx.x;
    int v = (i < CNT_N) ? cnt[i] : 0;
    #pragma unroll
    for (int m = 32; m >= 1; m >>= 1) v += __shfl_xor(v, m, 64);
    if ((threadIdx.x & 63) == 0) wsum[threadIdx.x >> 6] = v;
    __syncthreads();
    if (threadIdx.x == 0) part[blockIdx.x] = wsum[0] + wsum[1] + wsum[2] + wsum[3];
}
__global__ __launch_bounds__(256) void scan_tops2(int* __restrict__ part) {
    __shared__ int lds[256];
    int t = threadIdx.x;
    int v = (t < NSCB) ? part[t] : 0;
    lds[t] = v;
    __syncthreads();
    for (int s = 1; s < 256; s <<= 1) {
        int u = (t >= s) ? lds[t - s] : 0;
        __syncthreads();
        lds[t] += u;
        __syncthreads();
    }
    if (t < NSCB) part[t] = lds[t] - v;
}
__global__ __launch_bounds__(256) void scan_write2(int* __restrict__ cnt,
                                                   const int* __restrict__ part) {
    __shared__ int lds[256];
    int t = threadIdx.x;
    int i = blockIdx.x * 256 + t;
    int d = (i < CNT_N) ? cnt[i] : 0;
    lds[t] = d;
    __syncthreads();
    for (int s = 1; s < 256; s <<= 1) {
        int u = (t >= s) ? lds[t - s] : 0;
        __syncthreads();
        lds[t] += u;
        __syncthreads();
    }
    if (i < CNT_N) cnt[i] = part[blockIdx.x] + lds[t] - d;
}

// bfill: place packed records (c_local<<16 | row) into per-(block,bucket) runs
__global__ __launch_bounds__(256) void bfill(const int* __restrict__ row,
                                             const int* __restrict__ col,
                                             const int* __restrict__ cnt,
                                             uint_t* __restrict__ rec) {
    __shared__ int cur[NBUCK];
    int tid = threadIdx.x, blk = blockIdx.x;
    for (int i = tid; i < NBUCK; i += 256) cur[i] = cnt[i * NFB + blk];
    __syncthreads();
    int e0 = blk * EPB;
    for (int i = tid; i < EPB; i += 256) {
        int r = row[e0 + i], c = col[e0 + i];
        int pos = atomicAdd(&cur[c >> 8], 1);
        rec[pos] = ((uint_t)(c & 255) << 16) | (uint_t)r;
    }
}

// bdeg: dinv from bucket records via LDS histogram
__global__ __launch_bounds__(256) void bdeg(const uint_t* __restrict__ rec,
                                            const int* __restrict__ cnt,
                                            float* __restrict__ dinv) {
    __shared__ int hist[256];
    int tid = threadIdx.x, b = blockIdx.x;
    hist[tid] = 0;
    __syncthreads();
    int s = cnt[b * NFB];
    int e = (b + 1 < NBUCK) ? cnt[(b + 1) * NFB] : N_EDGES;
    for (int i = s + tid; i < e; i += 256) atomicAdd(&hist[rec[i] >> 16], 1);
    __syncthreads();
    int node = b * 256 + tid;
    if (node < N_NODES) {
        int d = hist[tid];
        dinv[node] = (d > 0) ? rsqrtf((float)d) : 0.f;
    }
}

// ---------------- MFMA encoder: h = x @ enc_w^T, x0 = h ----------------
template<typename T>
__global__ __launch_bounds__(256) void enc_mfma(const void* __restrict__ xin,
                                                const void* __restrict__ win,
                                                const uint_t* __restrict__ flag,
                                                T* __restrict__ h,
                                                T* __restrict__ x0) {
    __shared__ ushort_t As[64 * 72];
    __shared__ ushort_t Bs[64 * 72];
    bool isf32 = (*flag != 0u);
    int tid = threadIdx.x;
    int node0 = blockIdx.x * 64;
    int sr = tid >> 2, sc = (tid & 3) * 16;
    int w = tid >> 6, lane = tid & 63, m16 = lane & 15, quad = lane >> 4;
    f32x4 zero = {0.f, 0.f, 0.f, 0.f};
    f32x4 acc[4] = {zero, zero, zero, zero};

    for (int kb = 0; kb < 512; kb += 64) {
        int n = node0 + sr;
        stage16_in(xin, (size_t)n * NF, kb + sc, NF, isf32, n < N_NODES, &As[sr * 72 + sc]);
        stage16_in(win, (size_t)sr * NF, kb + sc, NF, isf32, true,        &Bs[sr * 72 + sc]);
        __syncthreads();
        #pragma unroll
        for (int k32 = 0; k32 < 64; k32 += 32) {
            short8 a = *(const short8*)&As[(w * 16 + m16) * 72 + k32 + quad * 8];
            #pragma unroll
            for (int t = 0; t < 4; t++) {
                short8 b = *(const short8*)&Bs[(t * 16 + m16) * 72 + k32 + quad * 8];
                acc[t] = __builtin_amdgcn_mfma_f32_16x16x32_bf16(a, b, acc[t], 0, 0, 0);
            }
        }
        __syncthreads();
    }
    #pragma unroll
    for (int r = 0; r < 4; r++) {
        int node = node0 + w * 16 + quad * 4 + r;
        if (node < N_NODES) {
            #pragma unroll
            for (int t = 0; t < 4; t++) {
                int f = t * 16 + m16;
                float v = acc[t][r];
                stv(&h[(size_t)node * 64 + f], v);
                stv(&x0[(size_t)node * 64 + f], v);
            }
        }
    }
}

// ---------------- MFMA layer GEMM: outp[n] = dinv[n]*(h @ W^T)[n], bf16 out ----------------
template<typename T>
__global__ __launch_bounds__(256) void gemm_mfma(const T* __restrict__ h,
                                                 const float* __restrict__ W,
                                                 const float* __restrict__ dinv,
                                                 ushort_t* __restrict__ outp) {
    __shared__ ushort_t Hs[64 * 72];
    __shared__ ushort_t Ws[64 * 72];
    int tid = threadIdx.x;
    int node0 = blockIdx.x * 64;
    int sr = tid >> 2, sc = (tid & 3) * 16;
    int w = tid >> 6, lane = tid & 63, m16 = lane & 15, quad = lane >> 4;

    {
        int n = node0 + sr;
        ushort_t* dh = &Hs[sr * 72 + sc];
        if (n < N_NODES) {
            if constexpr (sizeof(T) == 4) {
                const float4* p = (const float4*)((const float*)h + (size_t)n * 64 + sc);
                #pragma unroll
                for (int q = 0; q < 4; q++) {
                    float4 v = p[q];
                    dh[q * 4 + 0] = f2bf(v.x); dh[q * 4 + 1] = f2bf(v.y);
                    dh[q * 4 + 2] = f2bf(v.z); dh[q * 4 + 3] = f2bf(v.w);
                }
            } else {
                const uint4* p = (const uint4*)((const ushort_t*)h + (size_t)n * 64 + sc);
                uint4 v0 = p[0], v1 = p[1];
                ((uint4*)dh)[0] = v0;
                ((uint4*)dh)[1] = v1;
            }
        } else {
            #pragma unroll
            for (int i = 0; i < 16; i++) dh[i] = 0;
        }
        const float4* wp = (const float4*)(W + sr * 64 + sc);
        ushort_t* dw = &Ws[sr * 72 + sc];
        #pragma unroll
        for (int q = 0; q < 4; q++) {
            float4 v = wp[q];
            dw[q * 4 + 0] = f2bf(v.x); dw[q * 4 + 1] = f2bf(v.y);
            dw[q * 4 + 2] = f2bf(v.z); dw[q * 4 + 3] = f2bf(v.w);
        }
    }
    __syncthreads();

    f32x4 zero = {0.f, 0.f, 0.f, 0.f};
    f32x4 acc[4] = {zero, zero, zero, zero};
    #pragma unroll
    for (int k32 = 0; k32 < 64; k32 += 32) {
        short8 a = *(const short8*)&Hs[(w * 16 + m16) * 72 + k32 + quad * 8];
        #pragma unroll
        for (int t = 0; t < 4; t++) {
            short8 b = *(const short8*)&Ws[(t * 16 + m16) * 72 + k32 + quad * 8];
            acc[t] = __builtin_amdgcn_mfma_f32_16x16x32_bf16(a, b, acc[t], 0, 0, 0);
        }
    }
    #pragma unroll
    for (int r = 0; r < 4; r++) {
        int node = node0 + w * 16 + quad * 4 + r;
        if (node < N_NODES) {
            float dv = dinv[node];
            #pragma unroll
            for (int t = 0; t < 4; t++)
                outp[(size_t)node * 64 + t * 16 + m16] = f2bf(acc[t][r] * dv);
        }
    }
}

// ---------------- bucket aggregation + fused update ----------------
// block = bucket of 256 dst nodes; LDS acc tile 256x64 (stride 65), ds_add_f32
template<typename T>
__global__ __launch_bounds__(1024) void agg_bucket(T* __restrict__ h,
                                                   const T* __restrict__ x0,
                                                   const ushort_t* __restrict__ outp,
                                                   const float* __restrict__ dinv,
                                                   const int* __restrict__ cnt,
                                                   const uint_t* __restrict__ rec,
                                                   const void* __restrict__ extw,
                                                   const void* __restrict__ betap,
                                                   const uint_t* __restrict__ flag) {
    __shared__ float acc[256 * 65];
    __shared__ uint_t rs[1024];
    bool isf32 = (*flag != 0u);
    int tid = threadIdx.x, b = blockIdx.x;
    for (int i = tid; i < 256 * 65; i += 1024) acc[i] = 0.f;
    int s = cnt[b * NFB];
    int e = (b + 1 < NBUCK) ? cnt[(b + 1) * NFB] : N_EDGES;
    __syncthreads();

    const uint4* o128 = (const uint4*)outp;
    int eg = tid >> 3, l8 = tid & 7;       // eg: edge slot 0..127, l8: feature quad
    for (int base = s; base < e; base += 1024) {
        int m = e - base; if (m > 1024) m = 1024;
        if (base + tid < e) rs[tid] = rec[base + tid];
        __syncthreads();
        for (int st = 0; st < m; st += 128) {
            int idx = st + eg;
            if (idx < m) {
                uint_t rcd = rs[idx];
                int r = rcd & 0xFFFF;
                int cl = rcd >> 16;
                uint4 v = o128[(size_t)r * 8 + l8];
                float* ap = &acc[cl * 65 + l8 * 8];
                float2 p0 = bfpair2f2(v.x), p1 = bfpair2f2(v.y),
                       p2 = bfpair2f2(v.z), p3 = bfpair2f2(v.w);
                atomicAdd(&ap[0], p0.x); atomicAdd(&ap[1], p0.y);
                atomicAdd(&ap[2], p1.x); atomicAdd(&ap[3], p1.y);
                atomicAdd(&ap[4], p2.x); atomicAdd(&ap[5], p2.y);
                atomicAdd(&ap[6], p3.x); atomicAdd(&ap[7], p3.y);
            }
        }
        __syncthreads();
    }

    float beta = ldin(betap, 0, isf32);
    for (int i = tid; i < 256 * 64; i += 1024) {
        int nl = i >> 6, f = i & 63;
        int node = b * 256 + nl;
        if (node < N_NODES) {
            size_t gi = (size_t)node * 64 + f;
            float hv = ldv(&h[gi]);
            float conv = dinv[node] * acc[nl * 65 + f] - hv * ldin(extw, f, isf32)
                       + ldv(&x0[gi]) * beta;
            stv(&h[gi], hv + 0.1f * fmaxf(conv, 0.f));
        }
    }
}

// ---------------- decoder: out = h @ dec_w^T (f32 out) ----------------
template<typename T>
__global__ __launch_bounds__(256) void dec_k(const T* __restrict__ h,
                                             const void* __restrict__ dec,
                                             const uint_t* __restrict__ flag,
                                             float* __restrict__ out) {
    __shared__ float dsh[40 * 65];
    bool isf32 = (*flag != 0u);
    for (int i = threadIdx.x; i < NCLS * 64; i += 256) {
        int r = i >> 6, c = i & 63;
        dsh[r * 65 + c] = ldin(dec, i, isf32);
    }
    __syncthreads();
    int wv = threadIdx.x >> 6, c = threadIdx.x & 63;
    int n = blockIdx.x * 4 + wv;
    if (n < N_NODES && c < NCLS) {
        const T* hr = h + (size_t)n * 64;
        float acc = 0.f;
        #pragma unroll
        for (int k = 0; k < 64; k++) acc += ldv(&hr[k]) * dsh[c * 65 + k];
        out[(size_t)n * NCLS + c] = acc;
    }
}

template<typename T>
static void run_all(const void* x, const int* row, const int* col,
                    const void* enc_w, const void* dec_w,
                    const void* ext_w, const void* betap, const void* pw,
                    uint_t* flag, float* W, float* dinv,
                    int* cnt, int* part2, uint_t* rec,
                    ushort_t* outp, T* h, T* x0, float* out, hipStream_t stream) {
    detect_k<<<1, 256, 0, stream>>>((const uint_t*)x, flag);
    build_W<<<1, 64, 0, stream>>>(pw, flag, W);

    bcount<<<NFB, 256, 0, stream>>>(col, cnt);
    scan_part2<<<NSCB, 256, 0, stream>>>(cnt, part2);
    scan_tops2<<<1, 256, 0, stream>>>(part2);
    scan_write2<<<NSCB, 256, 0, stream>>>(cnt, part2);
    bfill<<<NFB, 256, 0, stream>>>(row, col, cnt, rec);
    bdeg<<<NBUCK, 256, 0, stream>>>(rec, cnt, dinv);

    enc_mfma<T><<<(N_NODES + 63) / 64, 256, 0, stream>>>(x, enc_w, flag, h, x0);

    for (int L = 0; L < 4; L++) {
        gemm_mfma<T><<<(N_NODES + 63) / 64, 256, 0, stream>>>(h, W, dinv, outp);
        agg_bucket<T><<<NBUCK, 1024, 0, stream>>>(h, x0, outp, dinv, cnt, rec,
                                                  ext_w, betap, flag);
    }

    dec_k<T><<<(N_NODES + 3) / 4, 256, 0, stream>>>(h, dec_w, flag, out);
}

extern "C" void kernel_launch(void* const* d_in, const int* in_sizes, int n_in,
                              void* d_out, int out_size, void* d_ws, size_t ws_size,
                              hipStream_t stream) {
    const void* x     = d_in[0];              // 50000x500 f32 (auto-detected)
    const int*  ei    = (const int*)d_in[1];  // 2 x 1.6M int32
    const void* enc_w = d_in[2];
    const void* dec_w = d_in[3];
    const void* ext_w = d_in[4];
    const void* betap = d_in[5];
    const void* pw    = d_in[6];

    const int* row  = ei;
    const int* colv = ei + N_EDGES;
    float*     out  = (float*)d_out;          // 50000x40 f32

    char* p = (char*)d_ws;
    uint_t* flag   = (uint_t*)p;               p += 16;
    float*  W      = (float*)p;                p += 4096 * sizeof(float);
    float*  dinv   = (float*)p;                p += N_NODES * sizeof(float);
    int*    cnt    = (int*)p;                  p += 39424 * sizeof(int);   // CNT_N padded
    int*    part2  = (int*)p;                  p += 256 * sizeof(int);
    uint_t* rec    = (uint_t*)p;               p += (size_t)N_EDGES * sizeof(uint_t);
    ushort_t* outp = (ushort_t*)p;             p += (size_t)NT * sizeof(ushort_t);
    size_t fixed = (size_t)(p - (char*)d_ws);

    size_t need32 = fixed + 2 * (size_t)NT * sizeof(float);   // h,x0 f32: ~38.2 MB
    if (ws_size >= need32) {
        float* h  = (float*)p;
        float* x0 = h + NT;
        run_all<float>(x, row, colv, enc_w, dec_w, ext_w, betap, pw,
                       flag, W, dinv, cnt, part2, rec, outp, h, x0, out, stream);
    } else {
        ushort_t* h  = (ushort_t*)p;           // bf16 tier: ~25.4 MB
        ushort_t* x0 = h + NT;
        run_all<ushort_t>(x, row, colv, enc_w, dec_w, ext_w, betap, pw,
                          flag, W, dinv, cnt, part2, rec, outp, h, x0, out, stream);
    }
}

// Round 9
// 510.496 us; speedup vs baseline: 6.1201x; 6.1201x over previous
//
#include <hip/hip_runtime.h>

#define N_NODES 50000
#define N_EDGES 1600000
#define NF 500
#define HID 64
#define NCLS 40
#define NT (N_NODES * HID)   // 3.2M
#define NBUCK 196            // ceil(N_NODES/256) destination buckets of 256 nodes
#define NFB 200              // fill blocks
#define EPB 8000             // edges per fill block (NFB*EPB == N_EDGES exact)
#define CNT_N (NBUCK * NFB)  // 39200
#define NSCB 154             // ceil(CNT_N/256)

typedef unsigned short ushort_t;
typedef unsigned int uint_t;
typedef __attribute__((ext_vector_type(8))) short short8;     // 8 bf16 (4 VGPRs)
typedef __attribute__((ext_vector_type(4))) float f32x4;      // MFMA acc

__device__ __forceinline__ float bf2f(ushort_t u) {
    union { uint_t i; float f; } v; v.i = ((uint_t)u) << 16; return v.f;
}
__device__ __forceinline__ ushort_t f2bf(float f) {
    union { float fl; uint_t i; } u; u.fl = f;
    uint_t lsb = (u.i >> 16) & 1u;
    return (ushort_t)((u.i + 0x7fffu + lsb) >> 16);   // RNE
}
__device__ __forceinline__ float2 bfpair2f2(uint_t u) {
    union { uint_t i; float f; } lo, hi;
    lo.i = (u & 0xffffu) << 16;
    hi.i = u & 0xffff0000u;
    float2 r; r.x = lo.f; r.y = hi.f; return r;
}

// scalar load/store for internal arrays: float (tier1) or bf16 (tier2)
template<typename T> __device__ __forceinline__ float ldv(const T* p);
template<> __device__ __forceinline__ float ldv<float>(const float* p) { return *p; }
template<> __device__ __forceinline__ float ldv<ushort_t>(const ushort_t* p) { return bf2f(*p); }
template<typename T> __device__ __forceinline__ void stv(T* p, float v);
template<> __device__ __forceinline__ void stv<float>(float* p, float v) { *p = v; }
template<> __device__ __forceinline__ void stv<ushort_t>(ushort_t* p, float v) { *p = f2bf(v); }

// 8-element vector load/store (16B/32B aligned)
template<typename T> __device__ __forceinline__ void ld8(const T* p, float* v);
template<> __device__ __forceinline__ void ld8<float>(const float* p, float* v) {
    float4 x = ((const float4*)p)[0], y = ((const float4*)p)[1];
    v[0]=x.x; v[1]=x.y; v[2]=x.z; v[3]=x.w; v[4]=y.x; v[5]=y.y; v[6]=y.z; v[7]=y.w;
}
template<> __device__ __forceinline__ void ld8<ushort_t>(const ushort_t* p, float* v) {
    uint4 u = *(const uint4*)p;
    float2 p0=bfpair2f2(u.x),p1=bfpair2f2(u.y),p2=bfpair2f2(u.z),p3=bfpair2f2(u.w);
    v[0]=p0.x; v[1]=p0.y; v[2]=p1.x; v[3]=p1.y; v[4]=p2.x; v[5]=p2.y; v[6]=p3.x; v[7]=p3.y;
}
template<typename T> __device__ __forceinline__ void st8(T* p, const float* v);
template<> __device__ __forceinline__ void st8<float>(float* p, const float* v) {
    float4 a, b;
    a.x=v[0]; a.y=v[1]; a.z=v[2]; a.w=v[3];
    b.x=v[4]; b.y=v[5]; b.z=v[6]; b.w=v[7];
    ((float4*)p)[0] = a; ((float4*)p)[1] = b;
}
template<> __device__ __forceinline__ void st8<ushort_t>(ushort_t* p, const float* v) {
    uint4 u;
    u.x = (uint_t)f2bf(v[0]) | ((uint_t)f2bf(v[1]) << 16);
    u.y = (uint_t)f2bf(v[2]) | ((uint_t)f2bf(v[3]) << 16);
    u.z = (uint_t)f2bf(v[4]) | ((uint_t)f2bf(v[5]) << 16);
    u.w = (uint_t)f2bf(v[6]) | ((uint_t)f2bf(v[7]) << 16);
    *(uint4*)p = u;
}

// dual-dtype input read (flag: 1 = f32, 0 = bf16)
__device__ __forceinline__ float ldin(const void* p, size_t idx, bool isf32) {
    return isf32 ? ((const float*)p)[idx] : bf2f(((const ushort_t*)p)[idx]);
}

// stage 16 input elements (global, dtype by flag) -> bf16 LDS
__device__ __forceinline__ void stage16_in(const void* src, size_t rowoff, int k0, int kmax,
                                           bool isf32, bool valid, ushort_t* dst) {
    if (valid && isf32 && (k0 + 16 <= kmax)) {
        const float4* p = (const float4*)((const float*)src + rowoff + k0);
        #pragma unroll
        for (int q = 0; q < 4; q++) {
            float4 v = p[q];
            dst[q * 4 + 0] = f2bf(v.x); dst[q * 4 + 1] = f2bf(v.y);
            dst[q * 4 + 2] = f2bf(v.z); dst[q * 4 + 3] = f2bf(v.w);
        }
    } else {
        #pragma unroll
        for (int i = 0; i < 16; i++) {
            int k = k0 + i;
            float v = (valid && k < kmax) ? ldin(src, rowoff + k, isf32) : 0.f;
            dst[i] = f2bf(v);
        }
    }
}

// accumulate a uint4 (8 bf16) into a[8]
__device__ __forceinline__ void acc8(uint4 u, float* a) {
    float2 p0=bfpair2f2(u.x),p1=bfpair2f2(u.y),p2=bfpair2f2(u.z),p3=bfpair2f2(u.w);
    a[0]+=p0.x; a[1]+=p0.y; a[2]+=p1.x; a[3]+=p1.y;
    a[4]+=p2.x; a[5]+=p2.y; a[6]+=p3.x; a[7]+=p3.y;
}

// ---------------- input dtype detector ----------------
__global__ void detect_k(const uint_t* __restrict__ xw, uint_t* __restrict__ flag) {
    __shared__ int cnt;
    if (threadIdx.x == 0) cnt = 0;
    __syncthreads();
    int odd = 0;
    for (int i = 0; i < 16; i++) {
        uint_t w = xw[threadIdx.x * 16 + i];
        uint_t e = (w >> 7) & 0xFFu;
        if (e > 170u || e < 84u) odd++;
    }
    atomicAdd(&cnt, odd);
    __syncthreads();
    if (threadIdx.x == 0) *flag = (cnt > 400) ? 1u : 0u;
}

// ---------------- W_eff build: 1 block x 64 ----------------
__global__ void build_W(const void* __restrict__ pw, const uint_t* __restrict__ flag,
                        float* __restrict__ W) {
    bool isf32 = (*flag != 0u);
    int i = threadIdx.x;
    float q = ldin(pw, i * 66 + 64, isf32);
    float r = ldin(pw, i * 66 + 65, isf32);
    float s = 0.f;
    for (int j = 0; j < 64; j++) {
        float v = 0.f;
        if (j > i)      v = ldin(pw, i * 66 + j, isf32);
        else if (j < i) v = ldin(pw, j * 66 + i, isf32);
        s += fabsf(v);
        W[i * 64 + j] = v;
    }
    W[i * 64 + i] = q * s + r;
}

// ---------------- bucketed edge build ----------------
__global__ __launch_bounds__(256) void bcount(const int* __restrict__ col,
                                              int* __restrict__ cnt) {
    __shared__ int hist[NBUCK];
    int tid = threadIdx.x, blk = blockIdx.x;
    for (int i = tid; i < NBUCK; i += 256) hist[i] = 0;
    __syncthreads();
    int e0 = blk * EPB;
    for (int i = tid; i < EPB; i += 256)
        atomicAdd(&hist[col[e0 + i] >> 8], 1);
    __syncthreads();
    for (int i = tid; i < NBUCK; i += 256) cnt[i * NFB + blk] = hist[i];
}

__global__ __launch_bounds__(256) void scan_part2(const int* __restrict__ cnt,
                                                  int* __restrict__ part) {
    __shared__ int wsum[4];
    int i = blockIdx.x * 256 + threadIdx.x;
    int v = (i < CNT_N) ? cnt[i] : 0;
    #pragma unroll
    for (int m = 32; m >= 1; m >>= 1) v += __shfl_xor(v, m, 64);
    if ((threadIdx.x & 63) == 0) wsum[threadIdx.x >> 6] = v;
    __syncthreads();
    if (threadIdx.x == 0) part[blockIdx.x] = wsum[0] + wsum[1] + wsum[2] + wsum[3];
}
__global__ __launch_bounds__(256) void scan_tops2(int* __restrict__ part) {
    __shared__ int lds[256];
    int t = threadIdx.x;
    int v = (t < NSCB) ? part[t] : 0;
    lds[t] = v;
    __syncthreads();
    for (int s = 1; s < 256; s <<= 1) {
        int u = (t >= s) ? lds[t - s] : 0;
        __syncthreads();
        lds[t] += u;
        __syncthreads();
    }
    if (t < NSCB) part[t] = lds[t] - v;
}
__global__ __launch_bounds__(256) void scan_write2(int* __restrict__ cnt,
                                                   const int* __restrict__ part) {
    __shared__ int lds[256];
    int t = threadIdx.x;
    int i = blockIdx.x * 256 + t;
    int d = (i < CNT_N) ? cnt[i] : 0;
    lds[t] = d;
    __syncthreads();
    for (int s = 1; s < 256; s <<= 1) {
        int u = (t >= s) ? lds[t - s] : 0;
        __syncthreads();
        lds[t] += u;
        __syncthreads();
    }
    if (i < CNT_N) cnt[i] = part[blockIdx.x] + lds[t] - d;
}

// bfill: place packed records (c_local<<16 | row) into per-(block,bucket) runs
__global__ __launch_bounds__(256) void bfill(const int* __restrict__ row,
                                             const int* __restrict__ col,
                                             const int* __restrict__ cnt,
                                             uint_t* __restrict__ rec) {
    __shared__ int cur[NBUCK];
    int tid = threadIdx.x, blk = blockIdx.x;
    for (int i = tid; i < NBUCK; i += 256) cur[i] = cnt[i * NFB + blk];
    __syncthreads();
    int e0 = blk * EPB;
    for (int i = tid; i < EPB; i += 256) {
        int r = row[e0 + i], c = col[e0 + i];
        int pos = atomicAdd(&cur[c >> 8], 1);
        rec[pos] = ((uint_t)(c & 255) << 16) | (uint_t)r;
    }
}

// csr_k: per-bucket counting sort -> off/eids/dinv (all writes in bucket window)
__global__ __launch_bounds__(256) void csr_k(const uint_t* __restrict__ rec,
                                             const int* __restrict__ cnt,
                                             int* __restrict__ off,
                                             uint_t* __restrict__ eids,
                                             float* __restrict__ dinv) {
    __shared__ int hist[256];
    __shared__ int scn[256];
    __shared__ int cur[256];
    int tid = threadIdx.x, b = blockIdx.x;
    hist[tid] = 0;
    __syncthreads();
    int s = cnt[b * NFB];
    int e = (b + 1 < NBUCK) ? cnt[(b + 1) * NFB] : N_EDGES;
    for (int i = s + tid; i < e; i += 256) atomicAdd(&hist[rec[i] >> 16], 1);
    __syncthreads();
    int d = hist[tid];
    scn[tid] = d;
    __syncthreads();
    for (int st = 1; st < 256; st <<= 1) {
        int v = (tid >= st) ? scn[tid - st] : 0;
        __syncthreads();
        scn[tid] += v;
        __syncthreads();
    }
    int excl = scn[tid] - d;
    cur[tid] = s + excl;
    int node = b * 256 + tid;
    if (node < N_NODES) {
        off[node] = s + excl;
        dinv[node] = (d > 0) ? rsqrtf((float)d) : 0.f;
        if (node == N_NODES - 1) off[N_NODES] = N_EDGES;
    }
    __syncthreads();
    for (int i = s + tid; i < e; i += 256) {
        uint_t rcd = rec[i];
        int pos = atomicAdd(&cur[rcd >> 16], 1);
        eids[pos] = rcd & 0xFFFFu;   // row id < 65536? NO: row < 50000 but 16 bits max 65535 — ok
    }
}

// ---------------- MFMA encoder: h = x @ enc_w^T, x0 = h ----------------
template<typename T>
__global__ __launch_bounds__(256) void enc_mfma(const void* __restrict__ xin,
                                                const void* __restrict__ win,
                                                const uint_t* __restrict__ flag,
                                                T* __restrict__ h,
                                                T* __restrict__ x0) {
    __shared__ ushort_t As[64 * 72];
    __shared__ ushort_t Bs[64 * 72];
    bool isf32 = (*flag != 0u);
    int tid = threadIdx.x;
    int node0 = blockIdx.x * 64;
    int sr = tid >> 2, sc = (tid & 3) * 16;
    int w = tid >> 6, lane = tid & 63, m16 = lane & 15, quad = lane >> 4;
    f32x4 zero = {0.f, 0.f, 0.f, 0.f};
    f32x4 acc[4] = {zero, zero, zero, zero};

    for (int kb = 0; kb < 512; kb += 64) {
        int n = node0 + sr;
        stage16_in(xin, (size_t)n * NF, kb + sc, NF, isf32, n < N_NODES, &As[sr * 72 + sc]);
        stage16_in(win, (size_t)sr * NF, kb + sc, NF, isf32, true,        &Bs[sr * 72 + sc]);
        __syncthreads();
        #pragma unroll
        for (int k32 = 0; k32 < 64; k32 += 32) {
            short8 a = *(const short8*)&As[(w * 16 + m16) * 72 + k32 + quad * 8];
            #pragma unroll
            for (int t = 0; t < 4; t++) {
                short8 b = *(const short8*)&Bs[(t * 16 + m16) * 72 + k32 + quad * 8];
                acc[t] = __builtin_amdgcn_mfma_f32_16x16x32_bf16(a, b, acc[t], 0, 0, 0);
            }
        }
        __syncthreads();
    }
    #pragma unroll
    for (int r = 0; r < 4; r++) {
        int node = node0 + w * 16 + quad * 4 + r;
        if (node < N_NODES) {
            #pragma unroll
            for (int t = 0; t < 4; t++) {
                int f = t * 16 + m16;
                float v = acc[t][r];
                stv(&h[(size_t)node * 64 + f], v);
                stv(&x0[(size_t)node * 64 + f], v);
            }
        }
    }
}

// ---------------- MFMA layer GEMM: outp[n] = dinv[n]*(h @ W^T)[n], bf16 out ----------------
template<typename T>
__global__ __launch_bounds__(256) void gemm_mfma(const T* __restrict__ h,
                                                 const float* __restrict__ W,
                                                 const float* __restrict__ dinv,
                                                 ushort_t* __restrict__ outp) {
    __shared__ ushort_t Hs[64 * 72];
    __shared__ ushort_t Ws[64 * 72];
    int tid = threadIdx.x;
    int node0 = blockIdx.x * 64;
    int sr = tid >> 2, sc = (tid & 3) * 16;
    int w = tid >> 6, lane = tid & 63, m16 = lane & 15, quad = lane >> 4;

    {
        int n = node0 + sr;
        ushort_t* dh = &Hs[sr * 72 + sc];
        if (n < N_NODES) {
            if constexpr (sizeof(T) == 4) {
                const float4* p = (const float4*)((const float*)h + (size_t)n * 64 + sc);
                #pragma unroll
                for (int q = 0; q < 4; q++) {
                    float4 v = p[q];
                    dh[q * 4 + 0] = f2bf(v.x); dh[q * 4 + 1] = f2bf(v.y);
                    dh[q * 4 + 2] = f2bf(v.z); dh[q * 4 + 3] = f2bf(v.w);
                }
            } else {
                const uint4* p = (const uint4*)((const ushort_t*)h + (size_t)n * 64 + sc);
                uint4 v0 = p[0], v1 = p[1];
                ((uint4*)dh)[0] = v0;
                ((uint4*)dh)[1] = v1;
            }
        } else {
            #pragma unroll
            for (int i = 0; i < 16; i++) dh[i] = 0;
        }
        const float4* wp = (const float4*)(W + sr * 64 + sc);
        ushort_t* dw = &Ws[sr * 72 + sc];
        #pragma unroll
        for (int q = 0; q < 4; q++) {
            float4 v = wp[q];
            dw[q * 4 + 0] = f2bf(v.x); dw[q * 4 + 1] = f2bf(v.y);
            dw[q * 4 + 2] = f2bf(v.z); dw[q * 4 + 3] = f2bf(v.w);
        }
    }
    __syncthreads();

    f32x4 zero = {0.f, 0.f, 0.f, 0.f};
    f32x4 acc[4] = {zero, zero, zero, zero};
    #pragma unroll
    for (int k32 = 0; k32 < 64; k32 += 32) {
        short8 a = *(const short8*)&Hs[(w * 16 + m16) * 72 + k32 + quad * 8];
        #pragma unroll
        for (int t = 0; t < 4; t++) {
            short8 b = *(const short8*)&Ws[(t * 16 + m16) * 72 + k32 + quad * 8];
            acc[t] = __builtin_amdgcn_mfma_f32_16x16x32_bf16(a, b, acc[t], 0, 0, 0);
        }
    }
    #pragma unroll
    for (int r = 0; r < 4; r++) {
        int node = node0 + w * 16 + quad * 4 + r;
        if (node < N_NODES) {
            float dv = dinv[node];
            #pragma unroll
            for (int t = 0; t < 4; t++)
                outp[(size_t)node * 64 + t * 16 + m16] = f2bf(acc[t][r] * dv);
        }
    }
}

// ---------------- fused gather + update: one wave/node, 8 lanes/edge x uint4 ----------------
template<typename T>
__global__ __launch_bounds__(256) void fused_agg(T* __restrict__ h,
                                                 const T* __restrict__ x0,
                                                 const ushort_t* __restrict__ outp,
                                                 const float* __restrict__ dinv,
                                                 const int* __restrict__ off,
                                                 const uint_t* __restrict__ eids,
                                                 const void* __restrict__ extw,
                                                 const void* __restrict__ betap,
                                                 const uint_t* __restrict__ flag) {
    bool isf32 = (*flag != 0u);
    int tid = threadIdx.x;
    int lane = tid & 63, wv = tid >> 6;
    int c = blockIdx.x * 4 + wv;            // grid exact: 12500*4 = 50000
    int s = off[c], e = off[c + 1];
    int deg = e - s;
    int g = lane >> 3, l8 = lane & 7;       // group = edge slot, l8 = feature-quad
    const uint4* o128 = (const uint4*)outp; // 8 x uint4 per node row (128 B)
    float a[8] = {0,0,0,0,0,0,0,0};

    for (int base = 0; base < deg; base += 64) {
        int cnt = deg - base; if (cnt > 64) cnt = 64;
        int eid = (base + lane < deg) ? (int)eids[s + base + lane] : 0;
        int k = 0;
        for (; k + 16 <= cnt; k += 16) {      // 16 edges, 2 loads in flight/lane
            int r0 = __shfl(eid, k + g, 64);
            int r1 = __shfl(eid, k + 8 + g, 64);
            uint4 v0 = o128[(size_t)r0 * 8 + l8];
            uint4 v1 = o128[(size_t)r1 * 8 + l8];
            acc8(v0, a); acc8(v1, a);
        }
        for (; k + 8 <= cnt; k += 8) {
            int r0 = __shfl(eid, k + g, 64);
            uint4 v0 = o128[(size_t)r0 * 8 + l8];
            acc8(v0, a);
        }
        if (k < cnt) {                        // tail < 8 edges
            int src = k + g;
            int srcc = (src < cnt) ? src : (cnt - 1);
            int r0 = __shfl(eid, srcc, 64);   // uniform participation
            if (src < cnt) {
                uint4 v0 = o128[(size_t)r0 * 8 + l8];
                acc8(v0, a);
            }
        }
    }
    // reduce the 8 edge-groups
    #pragma unroll
    for (int m = 8; m <= 32; m <<= 1) {
        #pragma unroll
        for (int i = 0; i < 8; i++) a[i] += __shfl_xor(a[i], m, 64);
    }

    if (g == 0) {                             // lanes 0..7 update 8 features each
        int f0 = l8 * 8;
        float beta = ldin(betap, 0, isf32);
        float dc = dinv[c];
        size_t idx = (size_t)c * 64 + f0;
        float hv[8], xv[8];
        ld8(&h[idx], hv);
        ld8(&x0[idx], xv);
        #pragma unroll
        for (int i = 0; i < 8; i++) {
            float ext = ldin(extw, f0 + i, isf32);
            float conv = dc * a[i] - hv[i] * ext + xv[i] * beta;
            hv[i] += 0.1f * fmaxf(conv, 0.f);
        }
        st8(&h[idx], hv);
    }
}

// ---------------- decoder: out = h @ dec_w^T (f32 out) ----------------
template<typename T>
__global__ __launch_bounds__(256) void dec_k(const T* __restrict__ h,
                                             const void* __restrict__ dec,
                                             const uint_t* __restrict__ flag,
                                             float* __restrict__ out) {
    __shared__ float dsh[40 * 65];
    bool isf32 = (*flag != 0u);
    for (int i = threadIdx.x; i < NCLS * 64; i += 256) {
        int r = i >> 6, c = i & 63;
        dsh[r * 65 + c] = ldin(dec, i, isf32);
    }
    __syncthreads();
    int wv = threadIdx.x >> 6, c = threadIdx.x & 63;
    int n = blockIdx.x * 4 + wv;
    if (n < N_NODES && c < NCLS) {
        const T* hr = h + (size_t)n * 64;
        float acc = 0.f;
        #pragma unroll
        for (int k = 0; k < 64; k++) acc += ldv(&hr[k]) * dsh[c * 65 + k];
        out[(size_t)n * NCLS + c] = acc;
    }
}

template<typename T>
static void run_all(const void* x, const int* row, const int* col,
                    const void* enc_w, const void* dec_w,
                    const void* ext_w, const void* betap, const void* pw,
                    uint_t* flag, float* W, float* dinv,
                    int* cnt, int* part2, uint_t* rec, int* off, uint_t* eids,
                    ushort_t* outp, T* h, T* x0, float* out, hipStream_t stream) {
    detect_k<<<1, 256, 0, stream>>>((const uint_t*)x, flag);
    build_W<<<1, 64, 0, stream>>>(pw, flag, W);

    bcount<<<NFB, 256, 0, stream>>>(col, cnt);
    scan_part2<<<NSCB, 256, 0, stream>>>(cnt, part2);
    scan_tops2<<<1, 256, 0, stream>>>(part2);
    scan_write2<<<NSCB, 256, 0, stream>>>(cnt, part2);
    bfill<<<NFB, 256, 0, stream>>>(row, col, cnt, rec);
    csr_k<<<NBUCK, 256, 0, stream>>>(rec, cnt, off, eids, dinv);

    enc_mfma<T><<<(N_NODES + 63) / 64, 256, 0, stream>>>(x, enc_w, flag, h, x0);

    for (int L = 0; L < 4; L++) {
        gemm_mfma<T><<<(N_NODES + 63) / 64, 256, 0, stream>>>(h, W, dinv, outp);
        fused_agg<T><<<(N_NODES + 3) / 4, 256, 0, stream>>>(h, x0, outp, dinv, off, eids,
                                                            ext_w, betap, flag);
    }

    dec_k<T><<<(N_NODES + 3) / 4, 256, 0, stream>>>(h, dec_w, flag, out);
}

extern "C" void kernel_launch(void* const* d_in, const int* in_sizes, int n_in,
                              void* d_out, int out_size, void* d_ws, size_t ws_size,
                              hipStream_t stream) {
    const void* x     = d_in[0];              // 50000x500 f32 (auto-detected)
    const int*  ei    = (const int*)d_in[1];  // 2 x 1.6M int32
    const void* enc_w = d_in[2];
    const void* dec_w = d_in[3];
    const void* ext_w = d_in[4];
    const void* betap = d_in[5];
    const void* pw    = d_in[6];

    const int* row  = ei;
    const int* colv = ei + N_EDGES;
    float*     out  = (float*)d_out;          // 50000x40 f32

    char* p = (char*)d_ws;
    uint_t* flag   = (uint_t*)p;               p += 16;
    float*  W      = (float*)p;                p += 4096 * sizeof(float);
    float*  dinv   = (float*)p;                p += N_NODES * sizeof(float);
    int*    cnt    = (int*)p;                  p += 39424 * sizeof(int);   // CNT_N padded
    int*    part2  = (int*)p;                  p += 256 * sizeof(int);
    int*    off    = (int*)p;                  p += 50004 * sizeof(int);
    uint_t* rec    = (uint_t*)p;               p += (size_t)N_EDGES * sizeof(uint_t);
    uint_t* eids   = (uint_t*)p;               p += (size_t)N_EDGES * sizeof(uint_t);
    ushort_t* outp = (ushort_t*)p;             p += (size_t)NT * sizeof(ushort_t);
    size_t fixed = (size_t)(p - (char*)d_ws);

    size_t need32 = fixed + 2 * (size_t)NT * sizeof(float);   // h,x0 f32
    if (ws_size >= need32) {
        float* h  = (float*)p;
        float* x0 = h + NT;
        run_all<float>(x, row, colv, enc_w, dec_w, ext_w, betap, pw,
                       flag, W, dinv, cnt, part2, rec, off, eids, outp, h, x0, out, stream);
    } else {
        ushort_t* h  = (ushort_t*)p;           // bf16 tier
        ushort_t* x0 = h + NT;
        run_all<ushort_t>(x, row, colv, enc_w, dec_w, ext_w, betap, pw,
                          flag, W, dinv, cnt, part2, rec, off, eids, outp, h, x0, out, stream);
    }
}